// Round 7
// baseline (1098.706 us; speedup 1.0000x reference)
//
#include <hip/hip_runtime.h>
#include <hip/hip_fp16.h>
#include <math.h>
#include <float.h>

#define NN 100000
#define NE 1600000

#define SCAN_T 256
#define SCAN_E 1024
#define SCAN_NB ((NN + SCAN_E - 1) / SCAN_E)   // 98

// ---------------- weight prepack: Wcat[i][g] = W_{g/OUT}[i][g%OUT] ----------------
__global__ __launch_bounds__(256)
void pack_w(const float* __restrict__ Wq, const float* __restrict__ Wk,
            const float* __restrict__ Wv, const float* __restrict__ Ws,
            const float* __restrict__ bq, const float* __restrict__ bk,
            const float* __restrict__ bv, const float* __restrict__ bs,
            float* __restrict__ Wcat, float* __restrict__ bcat,
            int IN_, int OUT_) {
    int NC = 4 * OUT_;
    int idx = blockIdx.x * 256 + threadIdx.x;
    if (idx >= (IN_ + 1) * NC) return;
    int row = idx / NC, col = idx % NC;
    int mat = col / OUT_, ch = col % OUT_;
    const float* W = (mat == 0) ? Wq : (mat == 1) ? Wk : (mat == 2) ? Wv : Ws;
    const float* B = (mat == 0) ? bq : (mat == 1) ? bk : (mat == 2) ? bv : bs;
    if (row < IN_) Wcat[(size_t)row * NC + col] = W[(size_t)row * OUT_ + ch];
    else           bcat[col] = B[ch];
}

// ---------------- fused linear: q,skip fp32; k,v packed fp16 ----------------
// block = 4*OUT threads (one thread per output column across all 4 matrices,
// zero lane waste). Thread accumulates NPT=16 nodes. Wcat: one coalesced
// 4B/lane load per k-row, reused across 16 nodes. x: wave-uniform float4.
template<int IN, int OUT, int NPT>
__global__ __launch_bounds__(4 * OUT)
void linear_fused(const float* __restrict__ x,
                  const float* __restrict__ Wcat, const float* __restrict__ bcat,
                  float* __restrict__ q, unsigned short* __restrict__ kv,
                  float* __restrict__ outskip) {
    constexpr int NC = 4 * OUT;
    const int g = threadIdx.x;                 // output column in [0, NC)
    const int node0 = blockIdx.x * NPT;
    const float* xrow = x + (size_t)node0 * IN;

    float acc[NPT];
    float bias = bcat[g];
#pragma unroll
    for (int p = 0; p < NPT; ++p) acc[p] = bias;

#pragma unroll
    for (int i0 = 0; i0 < IN; i0 += 4) {
        float w0 = Wcat[(size_t)(i0 + 0) * NC + g];
        float w1 = Wcat[(size_t)(i0 + 1) * NC + g];
        float w2 = Wcat[(size_t)(i0 + 2) * NC + g];
        float w3 = Wcat[(size_t)(i0 + 3) * NC + g];
#pragma unroll
        for (int p = 0; p < NPT; ++p) {
            float4 xv = *(const float4*)(xrow + p * IN + i0);  // wave-uniform
            acc[p] += xv.x * w0 + xv.y * w1 + xv.z * w2 + xv.w * w3;
        }
    }

    const int mat = g / OUT;                   // per-lane; <=2 mats per wave
    const int ch  = g % OUT;
#pragma unroll
    for (int p = 0; p < NPT; ++p) {
        float val = acc[p];
        float other = __shfl_xor(val, 1);      // all lanes participate
        if (mat == 0) {
            q[(size_t)(node0 + p) * OUT + ch] = val;
        } else if (mat == 3) {
            outskip[(size_t)(node0 + p) * OUT + ch] = val;
        } else if (!(g & 1)) {
            const int base = (mat == 1) ? 0 : OUT;
            unsigned lo  = __half_as_ushort(__float2half_rn(val));
            unsigned hiu = __half_as_ushort(__float2half_rn(other));
            *(unsigned*)(kv + (size_t)(node0 + p) * (2 * OUT) + base + ch)
                = lo | (hiu << 16);
        }
    }
}

// ---------------- CSR build (once; topology shared by all layers) ----------------
__global__ __launch_bounds__(256)
void hist_k(const int* __restrict__ ei, int* __restrict__ counts) {
    int e = blockIdx.x * blockDim.x + threadIdx.x;
    if (e < NE) atomicAdd(&counts[ei[NE + e]], 1);
}

__global__ __launch_bounds__(SCAN_T)
void scan1(const int* __restrict__ counts, int* __restrict__ offsets,
           int* __restrict__ blocksums) {
    __shared__ int lds[SCAN_T];
    int t = threadIdx.x;
    int base = blockIdx.x * SCAN_E + t * 4;
    int vals[4];
    int s = 0;
#pragma unroll
    for (int j = 0; j < 4; ++j) {
        int idx = base + j;
        vals[j] = (idx < NN) ? counts[idx] : 0;
        s += vals[j];
    }
    lds[t] = s;
    __syncthreads();
    for (int off = 1; off < SCAN_T; off <<= 1) {
        int xx = (t >= off) ? lds[t - off] : 0;
        __syncthreads();
        lds[t] += xx;
        __syncthreads();
    }
    int run = (t > 0) ? lds[t - 1] : 0;
    if (t == SCAN_T - 1) blocksums[blockIdx.x] = lds[t];
#pragma unroll
    for (int j = 0; j < 4; ++j) {
        int idx = base + j;
        if (idx < NN) offsets[idx] = run;
        run += vals[j];
    }
}

__global__ __launch_bounds__(128)
void scan2(int* __restrict__ blocksums) {
    __shared__ int lds[128];
    int t = threadIdx.x;
    lds[t] = (t < SCAN_NB) ? blocksums[t] : 0;
    __syncthreads();
    for (int off = 1; off < 128; off <<= 1) {
        int xx = (t >= off) ? lds[t - off] : 0;
        __syncthreads();
        lds[t] += xx;
        __syncthreads();
    }
    if (t < SCAN_NB) blocksums[t] = (t > 0) ? lds[t - 1] : 0;
}

__global__ __launch_bounds__(256)
void scan3(int* __restrict__ offsets, int* __restrict__ pos,
           const int* __restrict__ blocksums) {
    int i = blockIdx.x * blockDim.x + threadIdx.x;
    if (i < NN) {
        int o = offsets[i] + blocksums[i / SCAN_E];
        offsets[i] = o;
        pos[i] = o;
    }
    if (i == 0) offsets[NN] = NE;
}

__global__ __launch_bounds__(256)
void build_csr(const int* __restrict__ ei, int* __restrict__ pos,
               int* __restrict__ sorted_src) {
    int e = blockIdx.x * blockDim.x + threadIdx.x;
    if (e < NE) {
        int d = ei[NE + e];
        int p = atomicAdd(&pos[d], 1);
        sorted_src[p] = ei[e];
    }
}

// ---- 16-lane row sum via DPP rotates (VALU pipe, no LDS) ----
__device__ __forceinline__ float row16_sum(float x) {
    int y;
    y = __builtin_amdgcn_update_dpp(0, __float_as_int(x), 0x121, 0xF, 0xF, true); x += __int_as_float(y); // ror:1
    y = __builtin_amdgcn_update_dpp(0, __float_as_int(x), 0x122, 0xF, 0xF, true); x += __int_as_float(y); // ror:2
    y = __builtin_amdgcn_update_dpp(0, __float_as_int(x), 0x124, 0xF, 0xF, true); x += __int_as_float(y); // ror:4
    y = __builtin_amdgcn_update_dpp(0, __float_as_int(x), 0x128, 0xF, 0xF, true); x += __int_as_float(y); // ror:8
    return x;
}

__device__ __forceinline__ float4 h4_to_f4(uint2 w) {
    union { unsigned u; __half2 h; } a, b;
    a.u = w.x; b.u = w.y;
    float2 f0 = __half22float2(a.h);
    float2 f1 = __half22float2(b.h);
    return make_float4(f0.x, f0.y, f1.x, f1.y);
}

// ---------------- fused attention gather: one wave per node ----------------
// 4 independent 16-lane edge-groups with private online softmax; 2 edges per
// iteration per group, next pair prefetched -> up to 8 lines in flight/group.
template<int C, bool RELU>
__global__ __launch_bounds__(256)
void attn_gather(const int* __restrict__ offsets,
                 const int* __restrict__ sorted_src,
                 const float* __restrict__ q,
                 const unsigned short* __restrict__ kv,
                 float* __restrict__ out, float scale) {
    const int wid  = (int)((blockIdx.x * blockDim.x + threadIdx.x) >> 6);
    const int lane = threadIdx.x & 63;
    if (wid >= NN) return;
    const int grp = lane >> 4;
    const int ch  = (lane & 15) * 4;
    constexpr bool P2 = (C > 64);
    const bool hi = P2 && (ch + 64 < C);
    const float NEG = -1e30f;

    const int beg = offsets[wid], end = offsets[wid + 1];

    float4 qv0 = *(const float4*)(q + (size_t)wid * C + ch);
    float4 qv1 = make_float4(0.f, 0.f, 0.f, 0.f);
    if (hi) qv1 = *(const float4*)(q + (size_t)wid * C + ch + 64);

    float m = NEG, l = 0.f;
    float4 a0 = make_float4(0.f, 0.f, 0.f, 0.f);
    float4 a1 = make_float4(0.f, 0.f, 0.f, 0.f);

    int i = beg + grp;
    uint2 kw[2][2], vw[2][2];
#pragma unroll
    for (int s2 = 0; s2 < 2; ++s2) {
        kw[s2][0] = make_uint2(0, 0); vw[s2][0] = make_uint2(0, 0);
        kw[s2][1] = make_uint2(0, 0); vw[s2][1] = make_uint2(0, 0);
        int idx = i + 4 * s2;
        if (idx < end) {
            const unsigned short* row = kv + (size_t)sorted_src[idx] * (2 * C);
            kw[s2][0] = *(const uint2*)(row + ch);
            vw[s2][0] = *(const uint2*)(row + C + ch);
            if (hi) {
                kw[s2][1] = *(const uint2*)(row + 64 + ch);
                vw[s2][1] = *(const uint2*)(row + C + 64 + ch);
            }
        }
    }

    while (i < end) {
        int inext = i + 8;
        uint2 nkw[2][2], nvw[2][2];
#pragma unroll
        for (int s2 = 0; s2 < 2; ++s2) {
            nkw[s2][0] = make_uint2(0, 0); nvw[s2][0] = make_uint2(0, 0);
            nkw[s2][1] = make_uint2(0, 0); nvw[s2][1] = make_uint2(0, 0);
            int idx = inext + 4 * s2;
            if (idx < end) {
                const unsigned short* row = kv + (size_t)sorted_src[idx] * (2 * C);
                nkw[s2][0] = *(const uint2*)(row + ch);
                nvw[s2][0] = *(const uint2*)(row + C + ch);
                if (hi) {
                    nkw[s2][1] = *(const uint2*)(row + 64 + ch);
                    nvw[s2][1] = *(const uint2*)(row + C + 64 + ch);
                }
            }
        }

        float sc[2];
        float4 vf[2][2];
#pragma unroll
        for (int s2 = 0; s2 < 2; ++s2) {
            float4 kf0 = h4_to_f4(kw[s2][0]);
            vf[s2][0] = h4_to_f4(vw[s2][0]);
            float part = qv0.x * kf0.x + qv0.y * kf0.y + qv0.z * kf0.z + qv0.w * kf0.w;
            if (P2) {
                float4 kf1 = h4_to_f4(kw[s2][1]);
                vf[s2][1] = h4_to_f4(vw[s2][1]);
                part += qv1.x * kf1.x + qv1.y * kf1.y + qv1.z * kf1.z + qv1.w * kf1.w;
            }
            float s = row16_sum(part) * scale;
            sc[s2] = (i + 4 * s2 < end) ? s : NEG;
        }

        float mn = fmaxf(m, fmaxf(sc[0], sc[1]));
        float al = __expf(m - mn);
        float w0 = __expf(sc[0] - mn);
        float w1 = __expf(sc[1] - mn);
        l = l * al + w0 + w1;
        a0.x = a0.x * al + w0 * vf[0][0].x + w1 * vf[1][0].x;
        a0.y = a0.y * al + w0 * vf[0][0].y + w1 * vf[1][0].y;
        a0.z = a0.z * al + w0 * vf[0][0].z + w1 * vf[1][0].z;
        a0.w = a0.w * al + w0 * vf[0][0].w + w1 * vf[1][0].w;
        if (P2) {
            a1.x = a1.x * al + w0 * vf[0][1].x + w1 * vf[1][1].x;
            a1.y = a1.y * al + w0 * vf[0][1].y + w1 * vf[1][1].y;
            a1.z = a1.z * al + w0 * vf[0][1].z + w1 * vf[1][1].z;
            a1.w = a1.w * al + w0 * vf[0][1].w + w1 * vf[1][1].w;
        }
        m = mn;

#pragma unroll
        for (int s2 = 0; s2 < 2; ++s2) {
            kw[s2][0] = nkw[s2][0]; vw[s2][0] = nvw[s2][0];
            kw[s2][1] = nkw[s2][1]; vw[s2][1] = nvw[s2][1];
        }
        i = inext;
    }

    // merge the 4 groups: butterfly over lane-xor 16, 32
#pragma unroll
    for (int d = 16; d <= 32; d <<= 1) {
        float mo = __shfl_xor(m, d);
        float lo = __shfl_xor(l, d);
        float4 ao0, ao1;
        ao0.x = __shfl_xor(a0.x, d); ao0.y = __shfl_xor(a0.y, d);
        ao0.z = __shfl_xor(a0.z, d); ao0.w = __shfl_xor(a0.w, d);
        if (P2) {
            ao1.x = __shfl_xor(a1.x, d); ao1.y = __shfl_xor(a1.y, d);
            ao1.z = __shfl_xor(a1.z, d); ao1.w = __shfl_xor(a1.w, d);
        }
        float mn = fmaxf(m, mo);
        float e1 = (l  > 0.f) ? __expf(m  - mn) : 0.f;
        float e2 = (lo > 0.f) ? __expf(mo - mn) : 0.f;
        l = l * e1 + lo * e2;
        a0.x = a0.x * e1 + ao0.x * e2; a0.y = a0.y * e1 + ao0.y * e2;
        a0.z = a0.z * e1 + ao0.z * e2; a0.w = a0.w * e1 + ao0.w * e2;
        if (P2) {
            a1.x = a1.x * e1 + ao1.x * e2; a1.y = a1.y * e1 + ao1.y * e2;
            a1.z = a1.z * e1 + ao1.z * e2; a1.w = a1.w * e1 + ao1.w * e2;
        }
        m = mn;
    }

    if (lane < 16) {
        float inv = (l > 0.f) ? 1.f / l : 0.f;
        size_t o = (size_t)wid * C + ch;
        float4 sk = *(const float4*)(out + o);
        float4 r;
        r.x = sk.x + a0.x * inv; r.y = sk.y + a0.y * inv;
        r.z = sk.z + a0.z * inv; r.w = sk.w + a0.w * inv;
        if (RELU) {
            r.x = fmaxf(r.x, 0.f); r.y = fmaxf(r.y, 0.f);
            r.z = fmaxf(r.z, 0.f); r.w = fmaxf(r.w, 0.f);
        }
        *(float4*)(out + o) = r;
        if (hi) {
            float4 sk1 = *(const float4*)(out + o + 64);
            float4 r1;
            r1.x = sk1.x + a1.x * inv; r1.y = sk1.y + a1.y * inv;
            r1.z = sk1.z + a1.z * inv; r1.w = sk1.w + a1.w * inv;
            if (RELU) {
                r1.x = fmaxf(r1.x, 0.f); r1.y = fmaxf(r1.y, 0.f);
                r1.z = fmaxf(r1.z, 0.f); r1.w = fmaxf(r1.w, 0.f);
            }
            *(float4*)(out + o + 64) = r1;
        }
    }
}

// ---------------- host side ----------------
template<int IN, int OUT, bool RELU>
static void run_layer(const float* xin, const float* Wcat, const float* bcat,
                      const int* offsets, const int* sorted_src,
                      float* q, unsigned short* kv,
                      float* out, hipStream_t stream) {
    constexpr int NPT = 16;                    // NN = 6250 * 16 exactly
    linear_fused<IN, OUT, NPT><<<NN / NPT, 4 * OUT, 0, stream>>>(
        xin, Wcat, bcat, q, kv, out);

    float scale = 1.0f / sqrtf((float)OUT);
    attn_gather<OUT, RELU><<<(NN + 3) / 4, 256, 0, stream>>>(
        offsets, sorted_src, q, kv, out, scale);
}

extern "C" void kernel_launch(void* const* d_in, const int* in_sizes, int n_in,
                              void* d_out, int out_size, void* d_ws, size_t ws_size,
                              hipStream_t stream) {
    const float* x  = (const float*)d_in[0];
    const int*   ei = (const int*)d_in[1];
    const float* Wb0[8], *Wb1[8], *Wb2[8];
    for (int i = 0; i < 8; ++i) {
        Wb0[i] = (const float*)d_in[2 + i];
        Wb1[i] = (const float*)d_in[10 + i];
        Wb2[i] = (const float*)d_in[18 + i];
    }
    float* out = (float*)d_out;

    char* ws = (char*)d_ws;
    const size_t CMAX = 112;
    size_t off = 0;
    float*          q  = (float*)(ws + off);          off += (size_t)NN * CMAX * 4;
    unsigned short* kv = (unsigned short*)(ws + off); off += (size_t)NN * 2 * CMAX * 2;
    float* h0          = (float*)(ws + off);          off += (size_t)NN * 64 * 4;
    float* h1          = (float*)(ws + off);          off += (size_t)NN * 64 * 4;
    int*   sorted_src  = (int*)(ws + off);            off += (size_t)NE * 4;
    int*   counts      = (int*)(ws + off);            off += (size_t)NN * 4;
    int*   offsets     = (int*)(ws + off);            off += (size_t)(NN + 1) * 4;
    int*   pos         = (int*)(ws + off);            off += (size_t)NN * 4;
    int*   blocksums   = (int*)(ws + off);            off += (size_t)SCAN_NB * 4;
    float* Wcat0       = (float*)(ws + off);          off += (size_t)9  * 256 * 4;
    float* Wcat1       = (float*)(ws + off);          off += (size_t)65 * 256 * 4;
    float* Wcat2       = (float*)(ws + off);          off += (size_t)65 * 448 * 4;
    (void)ws_size; (void)in_sizes; (void)n_in; (void)out_size;
    float* bcat0 = Wcat0 + (size_t)8  * 256;
    float* bcat1 = Wcat1 + (size_t)64 * 256;
    float* bcat2 = Wcat2 + (size_t)64 * 448;

    // ---- prepack weights (tiny) ----
    pack_w<<<((8  + 1) * 256 + 255) / 256, 256, 0, stream>>>(
        Wb0[0], Wb0[2], Wb0[4], Wb0[6], Wb0[1], Wb0[3], Wb0[5], Wb0[7],
        Wcat0, bcat0, 8, 64);
    pack_w<<<((64 + 1) * 256 + 255) / 256, 256, 0, stream>>>(
        Wb1[0], Wb1[2], Wb1[4], Wb1[6], Wb1[1], Wb1[3], Wb1[5], Wb1[7],
        Wcat1, bcat1, 64, 64);
    pack_w<<<((64 + 1) * 448 + 255) / 256, 256, 0, stream>>>(
        Wb2[0], Wb2[2], Wb2[4], Wb2[6], Wb2[1], Wb2[3], Wb2[5], Wb2[7],
        Wcat2, bcat2, 64, 112);

    // ---- build CSR (grouped by dst) once ----
    hipMemsetAsync(counts, 0, (size_t)NN * sizeof(int), stream);
    hist_k<<<(NE + 255) / 256, 256, 0, stream>>>(ei, counts);
    scan1<<<SCAN_NB, SCAN_T, 0, stream>>>(counts, offsets, blocksums);
    scan2<<<1, 128, 0, stream>>>(blocksums);
    scan3<<<(NN + 255) / 256, 256, 0, stream>>>(offsets, pos, blocksums);
    build_csr<<<(NE + 255) / 256, 256, 0, stream>>>(ei, pos, sorted_src);

    run_layer<8,  64, true >(x,  Wcat0, bcat0, offsets, sorted_src, q, kv, h0,  stream);
    run_layer<64, 64, true >(h0, Wcat1, bcat1, offsets, sorted_src, q, kv, h1,  stream);
    run_layer<64, 112, false>(h1, Wcat2, bcat2, offsets, sorted_src, q, kv, out, stream);
}